// Round 23
// baseline (143.131 us; speedup 1.0000x reference)
//
#include <hip/hip_runtime.h>
#include <hip/hip_cooperative_groups.h>
#include <math.h>

#define ALPHA 0.001f
#define GAMMA 0.01f
#define DD 784
#define TD 1568          // 2*D floats per template row
#define RB 2048          // padded u8 row bytes (coded & templates)
#define MM 256
#define BB 1024
#define NCLS 10
#define ROWS_PB 4
#define TPW 4
#define NBLK 512         // cooperative: 2 blocks/CU x 256 CUs

// ws layout:
//   f32[0..511]    block min partials
//   f32[512..1023] block max partials
//   f32[1024..1279] scale[m]
//   i32[1280..1535] tsum[m]
//   i32[1536..2559] rowsum[row]
//   byte 16384:  u8 templates 256 x 2048  (512 KB)
//   byte 540672: u8 coded    1024 x 2048  (2 MB)

#define TMPL_OFF 16384
#define CODED_OFF 540672

static __device__ __forceinline__ unsigned sad_u8(unsigned a, unsigned b, unsigned c) {
  unsigned d;
  asm("v_sad_u8 %0, %1, %2, %3" : "=v"(d) : "v"(a), "v"(b), "v"(c));
  return d;
}

template <int CTRL, int RMASK>
static __device__ __forceinline__ int dpp_iadd(int v) {
  int t = __builtin_amdgcn_update_dpp(0, v, CTRL, RMASK, 0xf, false);
  return v + t;
}
static __device__ __forceinline__ int wave_isum64_lane63(int v) {
  v = dpp_iadd<0x111, 0xf>(v);   // row_shr:1
  v = dpp_iadd<0x112, 0xf>(v);   // row_shr:2
  v = dpp_iadd<0x114, 0xf>(v);   // row_shr:4
  v = dpp_iadd<0x118, 0xf>(v);   // row_shr:8
  v = dpp_iadd<0x142, 0xa>(v);   // row_bcast:15 -> rows 1,3
  v = dpp_iadd<0x143, 0xc>(v);   // row_bcast:31 -> rows 2,3
  return v;                      // lane 63 = full sum
}

static __device__ __forceinline__ unsigned q8(float v) {
  return (unsigned)(v * 255.f + 0.5f);   // v in [0,1]
}

__global__ __launch_bounds__(256, 2) void k_all(const float* __restrict__ x,
                                                const float* __restrict__ T,
                                                const int* __restrict__ committed,
                                                const int* __restrict__ counts,
                                                const int* __restrict__ labels,
                                                int* __restrict__ out_bits,
                                                float* __restrict__ ws) {
  cooperative_groups::grid_group grid = cooperative_groups::this_grid();
  int* iws = (int*)ws;

  __shared__ float smn[4], smx[4], sbc[2];
  __shared__ int rsum[4];
  __shared__ int clsmax[ROWS_PB][NCLS];

  int tid = threadIdx.x;
  int bid = blockIdx.x;
  int lane = tid & 63, wid = tid >> 6;
  int gid = bid * 256 + tid;

  // ================= phase 1: out_bits init + min/max partials ===========
  if (gid < BB * NCLS) out_bits[gid] = (int)0xFF800000;
  {
    const float4* x4 = (const float4*)x;
    const int n4 = BB * DD / 4;          // 200704
    float4 v = x4[gid];                  // gid < 131072 < n4 always
    float mn = fminf(fminf(v.x, v.y), fminf(v.z, v.w));
    float mx = fmaxf(fmaxf(v.x, v.y), fmaxf(v.z, v.w));
    int g2 = gid + NBLK * 256;
    if (g2 < n4) {
      float4 w = x4[g2];
      mn = fminf(mn, fminf(fminf(w.x, w.y), fminf(w.z, w.w)));
      mx = fmaxf(mx, fmaxf(fmaxf(w.x, w.y), fmaxf(w.z, w.w)));
    }
#pragma unroll
    for (int off = 32; off; off >>= 1) {
      mn = fminf(mn, __shfl_xor(mn, off, 64));
      mx = fmaxf(mx, __shfl_xor(mx, off, 64));
    }
    if (lane == 0) { smn[wid] = mn; smx[wid] = mx; }
    __syncthreads();
    if (tid == 0) {
      mn = fminf(fminf(smn[0], smn[1]), fminf(smn[2], smn[3]));
      mx = fmaxf(fmaxf(smx[0], smx[1]), fmaxf(smx[2], smx[3]));
      ws[bid] = mn;
      ws[NBLK + bid] = mx;
    }
  }
  grid.sync();

  // ========== phase 2a: every block reduces partials -> fmn/finv =========
  {
    float m2 = fminf(ws[tid], ws[tid + 256]);
    float x2 = fmaxf(ws[NBLK + tid], ws[NBLK + tid + 256]);
#pragma unroll
    for (int off = 32; off; off >>= 1) {
      m2 = fminf(m2, __shfl_xor(m2, off, 64));
      x2 = fmaxf(x2, __shfl_xor(x2, off, 64));
    }
    if (lane == 0) { smn[wid] = m2; smx[wid] = x2; }
    if (tid < 4) rsum[tid] = 0;
    __syncthreads();
    if (tid == 0) {
      m2 = fminf(fminf(smn[0], smn[1]), fminf(smn[2], smn[3]));
      x2 = fmaxf(fmaxf(smx[0], smx[1]), fmaxf(smx[2], smx[3]));
      sbc[0] = m2;
      sbc[1] = 1.0f / (x2 - m2 + 1e-10f);
    }
    __syncthreads();
  }
  float fmn = sbc[0], finv = sbc[1];
  float na = finv, nb = -fmn * finv;

  // ========== phase 2b: code slices (bid<256) / templates (256..319) =====
  if (bid < 256) {
    int row0 = bid * 4;                  // home XCD = bid % 8
    uint4* out4 = (uint4*)((char*)ws + CODED_OFF) + (size_t)bid * 512;
#pragma unroll
    for (int i = 0; i < 2; ++i) {
      int idx = i * 256 + tid;
      int r = idx >> 7;
      int u = idx & 127;
      uint4 o = make_uint4(0, 0, 0, 0);
      if (u < 98) {
        int half = (u >= 49);
        int e = (half ? (u - 49) : u) * 16;
        const float4* xr = (const float4*)(x + (size_t)(row0 + r) * DD + e);
        unsigned w[4];
        int isum = 0;
#pragma unroll
        for (int d = 0; d < 4; ++d) {
          float4 f = xr[d];
          float v0 = na * f.x + nb, v1 = na * f.y + nb;
          float v2 = na * f.z + nb, v3 = na * f.w + nb;
          if (half) { v0 = 1.f - v0; v1 = 1.f - v1; v2 = 1.f - v2; v3 = 1.f - v3; }
          unsigned b0 = q8(v0), b1 = q8(v1), b2 = q8(v2), b3 = q8(v3);
          isum += (int)(b0 + b1 + b2 + b3);
          w[d] = b0 | (b1 << 8) | (b2 << 16) | (b3 << 24);
        }
        o = make_uint4(w[0], w[1], w[2], w[3]);
        atomicAdd(&rsum[r], isum);
      }
      out4[idx] = o;
    }
    __syncthreads();
    if (tid < 4) iws[1536 + row0 + tid] = rsum[tid];
  } else if (bid < 320) {
    int m = (bid - 256) * 4 + wid;       // wave per template
    float s = 0.f;
    int isum = 0;
    uint4 pk[2] = {make_uint4(0,0,0,0), make_uint4(0,0,0,0)};
    if (lane < 49) {
      const float4* tp = (const float4*)(T + (size_t)m * TD + lane * 32);
      unsigned w[8];
#pragma unroll
      for (int d = 0; d < 8; ++d) {
        float4 f = tp[d];
        s += (f.x + f.y) + (f.z + f.w);
        unsigned b0 = q8(f.x), b1 = q8(f.y), b2 = q8(f.z), b3 = q8(f.w);
        isum += (int)(b0 + b1 + b2 + b3);
        w[d] = b0 | (b1 << 8) | (b2 << 16) | (b3 << 24);
      }
      pk[0] = make_uint4(w[0], w[1], w[2], w[3]);
      pk[1] = make_uint4(w[4], w[5], w[6], w[7]);
    }
    uint4* u8T = (uint4*)((char*)ws + TMPL_OFF + (size_t)m * RB);
    u8T[lane * 2]     = pk[0];
    u8T[lane * 2 + 1] = pk[1];
#pragma unroll
    for (int off = 32; off; off >>= 1) {
      s += __shfl_xor(s, off, 64);
      isum += __shfl_xor(isum, off, 64);
    }
    if (lane == 0) {
      float denom = ALPHA + s + GAMMA * (float)counts[m];
      ws[1024 + m] = committed[m] ? (1.0f / denom) : -1.0f;
      iws[1280 + m] = isum;
    }
  }
  grid.sync();

  // ================= phase 3: 8 tiles, fixed rowgroup per block ==========
  int rg = bid & 255;                    // XCD-aligned: reader XCD == writer XCD
  int row0 = rg * ROWS_PB;
  const uint4* tbase = (const uint4*)((const char*)ws + TMPL_OFF);
  const uint4* cgp = (const uint4*)((const char*)ws + CODED_OFF) + (size_t)row0 * 128;
  int myrow = iws[1536 + row0 + (lane & 3)];

  if (tid < ROWS_PB * NCLS) clsmax[tid / NCLS][tid % NCLS] = (int)0xFF800000;
  __syncthreads();

  for (int q = 0; q < 8; ++q) {
    int tile = q * NBLK + bid;           // rg = tile & 255 == bid & 255 (const)
    int tg = tile >> 8;                  // 0..15
    int m0 = tg * 16 + wid * TPW;

    uint4 tr[TPW][2], cr[ROWS_PB][2];
#pragma unroll
    for (int t = 0; t < TPW; ++t) {
      const uint4* a0 = tbase + (size_t)(m0 + t) * 128 + lane;
      const uint4* a1 = a0 + 64;
      asm volatile("global_load_dwordx4 %0, %1, off" : "=v"(tr[t][0]) : "v"(a0));
      asm volatile("global_load_dwordx4 %0, %1, off" : "=v"(tr[t][1]) : "v"(a1));
    }
#pragma unroll
    for (int r = 0; r < ROWS_PB; ++r) {
      const uint4* b0 = cgp + r * 128 + lane;
      const uint4* b1 = b0 + 64;
      asm volatile("global_load_dwordx4 %0, %1, off" : "=v"(cr[r][0]) : "v"(b0));
      asm volatile("global_load_dwordx4 %0, %1, off" : "=v"(cr[r][1]) : "v"(b1));
    }
    float scv[TPW];
    int lbv[TPW], tsv[TPW];
#pragma unroll
    for (int t = 0; t < TPW; ++t) {
      scv[t] = ws[1024 + m0 + t];
      lbv[t] = labels[m0 + t];
      tsv[t] = iws[1280 + m0 + t];
    }
    asm volatile("s_waitcnt vmcnt(0)" ::: "memory");
    __builtin_amdgcn_sched_barrier(0);

    unsigned acc[TPW][ROWS_PB];
#pragma unroll
    for (int t = 0; t < TPW; ++t)
#pragma unroll
      for (int r = 0; r < ROWS_PB; ++r) acc[t][r] = 0;

#pragma unroll
    for (int r = 0; r < ROWS_PB; ++r) {
#pragma unroll
      for (int t = 0; t < TPW; ++t) {
        unsigned a = acc[t][r];
        a = sad_u8(cr[r][0].x, tr[t][0].x, a);
        a = sad_u8(cr[r][0].y, tr[t][0].y, a);
        a = sad_u8(cr[r][0].z, tr[t][0].z, a);
        a = sad_u8(cr[r][0].w, tr[t][0].w, a);
        a = sad_u8(cr[r][1].x, tr[t][1].x, a);
        a = sad_u8(cr[r][1].y, tr[t][1].y, a);
        a = sad_u8(cr[r][1].z, tr[t][1].z, a);
        a = sad_u8(cr[r][1].w, tr[t][1].w, a);
        acc[t][r] = a;
      }
    }

    float sc = -1.f; int lb = 0, tsum_s = 0;
#pragma unroll
    for (int t = 0; t < TPW; ++t)
      if ((lane >> 2) == t) { sc = scv[t]; lb = lbv[t]; tsum_s = tsv[t]; }

    float vout = 0.f;
#pragma unroll
    for (int t = 0; t < TPW; ++t)
#pragma unroll
      for (int r = 0; r < ROWS_PB; ++r) {
        int s = wave_isum64_lane63((int)acc[t][r]);
        int g = __builtin_amdgcn_readlane(s, 63);
        if (lane == t * 4 + r)
          vout = (float)(myrow + tsum_s - g) * (sc * (0.5f / 255.f));
      }

    if (lane < 16 && sc > 0.f)
      atomicMax(&clsmax[lane & 3][lb], __float_as_int(vout));
  }

  __syncthreads();
  if (tid < ROWS_PB * NCLS) {
    int rr = tid / NCLS, cc = tid - rr * NCLS;
    int bits = clsmax[rr][cc];
    if (bits != (int)0xFF800000)
      atomicMax(&out_bits[(row0 + rr) * NCLS + cc], bits);
  }
}

extern "C" void kernel_launch(void* const* d_in, const int* in_sizes, int n_in,
                              void* d_out, int out_size, void* d_ws, size_t ws_size,
                              hipStream_t stream) {
  const float* x = (const float*)d_in[0];
  const float* T = (const float*)d_in[1];
  const int* committed = (const int*)d_in[2];
  const int* labels = (const int*)d_in[3];
  const int* counts = (const int*)d_in[4];
  int* out_bits = (int*)d_out;
  float* ws = (float*)d_ws;

  void* args[] = {(void*)&x, (void*)&T, (void*)&committed, (void*)&counts,
                  (void*)&labels, (void*)&out_bits, (void*)&ws};
  hipLaunchCooperativeKernel((const void*)k_all, dim3(NBLK), dim3(256),
                             args, 0, stream);
}

// Round 24
// 30.207 us; speedup vs baseline: 4.7384x; 4.7384x over previous
//
#include <hip/hip_runtime.h>
#include <math.h>

#define ALPHA 0.001f
#define GAMMA 0.01f
#define DD 784
#define TD 1568          // 2*D floats per template row
#define RB 2048          // padded u8 row bytes (coded & templates)
#define MM 256
#define BB 1024
#define NCLS 10
#define ROWS_PB 4
#define TPW 8
#define NBLK 2048        // 8 tgroups (high bits) x 256 rowgroups (low bits)

// ws layout:
//   f32[0..255] partial min | f32[256..511] partial max
//   f32[512..767] scale[m] | f32[768] min | f32[769] 1/(max-min+1e-10)
//   i32[1024..1279] tsum[m]
//   i32[1536..2559] rowsum[row]
//   byte 16384:  u8 templates 256 x 2048  (512 KB)
//   byte 540672: u8 coded    1024 x 2048  (2 MB)

#define TMPL_OFF 16384
#define CODED_OFF 540672

static __device__ __forceinline__ unsigned sad_u8(unsigned a, unsigned b, unsigned c) {
  unsigned d;
  asm("v_sad_u8 %0, %1, %2, %3" : "=v"(d) : "v"(a), "v"(b), "v"(c));
  return d;
}

template <int CTRL, int RMASK>
static __device__ __forceinline__ int dpp_iadd(int v) {
  int t = __builtin_amdgcn_update_dpp(0, v, CTRL, RMASK, 0xf, false);
  return v + t;
}
static __device__ __forceinline__ int wave_isum64_lane63(int v) {
  v = dpp_iadd<0x111, 0xf>(v);   // row_shr:1
  v = dpp_iadd<0x112, 0xf>(v);   // row_shr:2
  v = dpp_iadd<0x114, 0xf>(v);   // row_shr:4
  v = dpp_iadd<0x118, 0xf>(v);   // row_shr:8
  v = dpp_iadd<0x142, 0xa>(v);   // row_bcast:15 -> rows 1,3
  v = dpp_iadd<0x143, 0xc>(v);   // row_bcast:31 -> rows 2,3
  return v;                      // lane 63 = full sum
}

static __device__ __forceinline__ unsigned q8(float v) {
  return (unsigned)(v * 255.f + 0.5f);   // v in [0,1]
}

__global__ __launch_bounds__(256) void k_minmax(const float* __restrict__ x,
                                                float* __restrict__ ws,
                                                int* __restrict__ out_bits) {
  const float4* x4 = (const float4*)x;
  const int n4 = BB * DD / 4;
  int tid = blockIdx.x * 256 + threadIdx.x;
  if (tid < BB * NCLS) out_bits[tid] = (int)0xFF800000;  // -inf each launch
  float mn = 1e30f, mx = -1e30f;
  for (int i = tid; i < n4; i += 256 * 256) {
    float4 v = x4[i];
    mn = fminf(mn, fminf(fminf(v.x, v.y), fminf(v.z, v.w)));
    mx = fmaxf(mx, fmaxf(fmaxf(v.x, v.y), fmaxf(v.z, v.w)));
  }
#pragma unroll
  for (int off = 32; off; off >>= 1) {
    mn = fminf(mn, __shfl_xor(mn, off, 64));
    mx = fmaxf(mx, __shfl_xor(mx, off, 64));
  }
  __shared__ float smn[4], smx[4];
  int lane = threadIdx.x & 63, wid = threadIdx.x >> 6;
  if (lane == 0) { smn[wid] = mn; smx[wid] = mx; }
  __syncthreads();
  if (threadIdx.x == 0) {
    mn = fminf(fminf(smn[0], smn[1]), fminf(smn[2], smn[3]));
    mx = fmaxf(fmaxf(smx[0], smx[1]), fmaxf(smx[2], smx[3]));
    ws[blockIdx.x] = mn;
    ws[256 + blockIdx.x] = mx;
  }
}

// block per template m, 64 threads. Emits f32 scale, int tsum, u8 row.
// Block 0's wave ALSO finalizes the global min/max stats (replaces k_stats;
// k_code runs after this kernel and reads ws[768..769]).
__global__ __launch_bounds__(64) void k_denom(const float* __restrict__ T,
                                              const int* __restrict__ committed,
                                              const int* __restrict__ counts,
                                              float* __restrict__ ws) {
  int m = blockIdx.x;
  int lane = threadIdx.x;

  if (m == 0) {   // ---- stats finalize (single wave) ----
    float mn = 1e30f, mx = -1e30f;
    for (int i = lane; i < 256; i += 64) {
      mn = fminf(mn, ws[i]);
      mx = fmaxf(mx, ws[256 + i]);
    }
#pragma unroll
    for (int off = 32; off; off >>= 1) {
      mn = fminf(mn, __shfl_xor(mn, off, 64));
      mx = fmaxf(mx, __shfl_xor(mx, off, 64));
    }
    if (lane == 0) {
      ws[768] = mn;
      ws[769] = 1.0f / (mx - mn + 1e-10f);
    }
  }

  float s = 0.f;
  int isum = 0;
  uint4 pk[2] = {make_uint4(0,0,0,0), make_uint4(0,0,0,0)};
  if (lane < 49) {
    const float4* tp = (const float4*)(T + (size_t)m * TD + lane * 32);
    unsigned w[8];
#pragma unroll
    for (int d = 0; d < 8; ++d) {
      float4 f = tp[d];
      s += (f.x + f.y) + (f.z + f.w);
      unsigned b0 = q8(f.x), b1 = q8(f.y), b2 = q8(f.z), b3 = q8(f.w);
      isum += (int)(b0 + b1 + b2 + b3);
      w[d] = b0 | (b1 << 8) | (b2 << 16) | (b3 << 24);
    }
    pk[0] = make_uint4(w[0], w[1], w[2], w[3]);
    pk[1] = make_uint4(w[4], w[5], w[6], w[7]);
  }
  uint4* u8T = (uint4*)((char*)ws + TMPL_OFF + (size_t)m * RB);
  u8T[lane * 2]     = pk[0];
  u8T[lane * 2 + 1] = pk[1];
#pragma unroll
  for (int off = 32; off; off >>= 1) {
    s += __shfl_xor(s, off, 64);
    isum += __shfl_xor(isum, off, 64);
  }
  if (lane == 0) {
    float denom = ALPHA + s + GAMMA * (float)counts[m];
    ws[512 + m] = committed[m] ? (1.0f / denom) : -1.0f;
    ((int*)ws)[1024 + m] = isum;
  }
}

// One-shot quantize+pack of coded x rows. 256 blocks x 256 thr; block b
// owns rows 4b..4b+3 -> XCD b%8 (home XCD for that coded slice).
__global__ __launch_bounds__(256) void k_code(const float* __restrict__ x,
                                              float* __restrict__ ws) {
  __shared__ int rsum[4];
  int tid = threadIdx.x;
  if (tid < 4) rsum[tid] = 0;
  __syncthreads();
  float fmn = ws[768], finv = ws[769];
  float na = finv, nb = -fmn * finv;
  int row0 = blockIdx.x * 4;
  uint4* out4 = (uint4*)((char*)ws + CODED_OFF) + (size_t)blockIdx.x * 512;
#pragma unroll
  for (int i = 0; i < 2; ++i) {
    int idx = i * 256 + tid;           // 0..511
    int r = idx >> 7;
    int u = idx & 127;
    uint4 o = make_uint4(0, 0, 0, 0);
    if (u < 98) {
      int half = (u >= 49);
      int e = (half ? (u - 49) : u) * 16;
      const float4* xr = (const float4*)(x + (size_t)(row0 + r) * DD + e);
      unsigned w[4];
      int isum = 0;
#pragma unroll
      for (int d = 0; d < 4; ++d) {
        float4 f = xr[d];
        float v0 = na * f.x + nb, v1 = na * f.y + nb;
        float v2 = na * f.z + nb, v3 = na * f.w + nb;
        if (half) { v0 = 1.f - v0; v1 = 1.f - v1; v2 = 1.f - v2; v3 = 1.f - v3; }
        unsigned b0 = q8(v0), b1 = q8(v1), b2 = q8(v2), b3 = q8(v3);
        isum += (int)(b0 + b1 + b2 + b3);
        w[d] = b0 | (b1 << 8) | (b2 << 16) | (b3 << 24);
      }
      o = make_uint4(w[0], w[1], w[2], w[3]);
      atomicAdd(&rsum[r], isum);
    }
    out4[idx] = o;
  }
  __syncthreads();
  if (tid < 4) ((int*)ws)[1536 + row0 + tid] = rsum[tid];
}

// grid 2048; XCD-aligned decode: rg = bid & 255, tg = bid >> 8 (0..7).
// All 8 blocks reading rowgroup rg land on XCD rg%8 -- same as k_code's
// writer. Wave owns TPW=8 templates (16 asm loads) + 4 coded rows (8 asm
// loads): one drain, 256 SADs, 32 DPP reduces -> 32 outputs/wave.
// (R24 = R21 + TPW=8 ONLY -- isolating the one untested R22 component.)
__global__ __launch_bounds__(256) void k_main(const int* __restrict__ labels,
                                              const float* __restrict__ ws,
                                              int* __restrict__ out_bits) {
  __shared__ int clsmax[ROWS_PB][NCLS];

  int tid = threadIdx.x;
  int lane = tid & 63, wid = tid >> 6;
  int rg = blockIdx.x & 255;       // low bits -> XCD affinity follows rowgroup
  int tg = blockIdx.x >> 8;        // 0..7
  int row0 = rg * ROWS_PB;
  int m0 = tg * 32 + wid * TPW;

  // ---- issue ALL loads first: 16 template + 8 coded (inline asm) ----
  const uint4* tbase = (const uint4*)((const char*)ws + TMPL_OFF);
  const uint4* cg = (const uint4*)((const char*)ws + CODED_OFF) + (size_t)row0 * 128;
  uint4 tr[TPW][2], cr[ROWS_PB][2];
#pragma unroll
  for (int t = 0; t < TPW; ++t) {
    const uint4* a0 = tbase + (size_t)(m0 + t) * 128 + lane;
    const uint4* a1 = a0 + 64;
    asm volatile("global_load_dwordx4 %0, %1, off" : "=v"(tr[t][0]) : "v"(a0));
    asm volatile("global_load_dwordx4 %0, %1, off" : "=v"(tr[t][1]) : "v"(a1));
  }
#pragma unroll
  for (int r = 0; r < ROWS_PB; ++r) {
    const uint4* b0 = cg + r * 128 + lane;
    const uint4* b1 = b0 + 64;
    asm volatile("global_load_dwordx4 %0, %1, off" : "=v"(cr[r][0]) : "v"(b0));
    asm volatile("global_load_dwordx4 %0, %1, off" : "=v"(cr[r][1]) : "v"(b1));
  }

  // scalar-ish metadata loads (overlap with VMEM)
  float scv[TPW];
  int lbv[TPW], tsv[TPW];
#pragma unroll
  for (int t = 0; t < TPW; ++t) {
    scv[t] = ws[512 + m0 + t];
    lbv[t] = labels[m0 + t];
    tsv[t] = ((const int*)ws)[1024 + m0 + t];
  }
  int myrow = ((const int*)ws)[1536 + row0 + (lane & 3)];

  if (tid < ROWS_PB * NCLS) clsmax[tid / NCLS][tid % NCLS] = (int)0xFF800000;

  // single drain; fence register-only SAD from hoisting above (rule #18)
  asm volatile("s_waitcnt vmcnt(0)" ::: "memory");
  __builtin_amdgcn_sched_barrier(0);
  __syncthreads();   // clsmax init visible

  // ---- compute: 256 v_sad_u8, zero memory ops ----
  unsigned acc[TPW][ROWS_PB];
#pragma unroll
  for (int t = 0; t < TPW; ++t)
#pragma unroll
    for (int r = 0; r < ROWS_PB; ++r) acc[t][r] = 0;

#pragma unroll
  for (int r = 0; r < ROWS_PB; ++r) {
#pragma unroll
    for (int t = 0; t < TPW; ++t) {
      unsigned a = acc[t][r];
      a = sad_u8(cr[r][0].x, tr[t][0].x, a);
      a = sad_u8(cr[r][0].y, tr[t][0].y, a);
      a = sad_u8(cr[r][0].z, tr[t][0].z, a);
      a = sad_u8(cr[r][0].w, tr[t][0].w, a);
      a = sad_u8(cr[r][1].x, tr[t][1].x, a);
      a = sad_u8(cr[r][1].y, tr[t][1].y, a);
      a = sad_u8(cr[r][1].z, tr[t][1].z, a);
      a = sad_u8(cr[r][1].w, tr[t][1].w, a);
      acc[t][r] = a;
    }
  }

  // ---- reduce: 32 DPP sums; scatter lane = t*4+r computes choice ----
  float sc = -1.f; int lb = 0, tsum_s = 0;
#pragma unroll
  for (int t = 0; t < TPW; ++t)
    if ((lane >> 2) == t) { sc = scv[t]; lb = lbv[t]; tsum_s = tsv[t]; }

  float vout = 0.f;
#pragma unroll
  for (int t = 0; t < TPW; ++t)
#pragma unroll
    for (int r = 0; r < ROWS_PB; ++r) {
      int s = wave_isum64_lane63((int)acc[t][r]);
      int g = __builtin_amdgcn_readlane(s, 63);
      if (lane == t * 4 + r)
        vout = (float)(myrow + tsum_s - g) * (sc * (0.5f / 255.f));
    }

  if (lane < 32 && sc > 0.f)
    atomicMax(&clsmax[lane & 3][lb], __float_as_int(vout));
  __syncthreads();

  if (tid < ROWS_PB * NCLS) {
    int rr = tid / NCLS, cc = tid - rr * NCLS;
    int bits = clsmax[rr][cc];
    if (bits != (int)0xFF800000)
      atomicMax(&out_bits[(row0 + rr) * NCLS + cc], bits);
  }
}

extern "C" void kernel_launch(void* const* d_in, const int* in_sizes, int n_in,
                              void* d_out, int out_size, void* d_ws, size_t ws_size,
                              hipStream_t stream) {
  const float* x = (const float*)d_in[0];
  const float* T = (const float*)d_in[1];
  const int* committed = (const int*)d_in[2];
  const int* labels = (const int*)d_in[3];
  const int* counts = (const int*)d_in[4];
  int* out_bits = (int*)d_out;
  float* ws = (float*)d_ws;

  k_minmax<<<dim3(256), dim3(256), 0, stream>>>(x, ws, out_bits);
  k_denom<<<dim3(256), dim3(64), 0, stream>>>(T, committed, counts, ws);
  k_code<<<dim3(256), dim3(256), 0, stream>>>(x, ws);
  k_main<<<dim3(NBLK), dim3(256), 0, stream>>>(labels, ws, out_bits);
}

// Round 25
// 26.928 us; speedup vs baseline: 5.3153x; 1.1218x over previous
//
#include <hip/hip_runtime.h>
#include <math.h>

#define ALPHA 0.001f
#define GAMMA 0.01f
#define DD 784
#define TD 1568          // 2*D floats per template row
#define RB 2048          // padded u8 row bytes (coded & templates)
#define MM 256
#define BB 1024
#define NCLS 10
#define ROWS_PB 4
#define TPW 4
#define NBLK 4096        // 16 tgroups (high bits) x 256 rowgroups (low bits)

// ws layout:
//   f32[0..255] partial min | f32[256..511] partial max
//   f32[512..767] scale[m]
//   i32[1024..1279] tsum[m]
//   i32[1536..2559] rowsum[row]
//   byte 16384:  u8 templates 256 x 2048  (512 KB)
//   byte 540672: u8 coded    1024 x 2048  (2 MB)

#define TMPL_OFF 16384
#define CODED_OFF 540672

static __device__ __forceinline__ unsigned sad_u8(unsigned a, unsigned b, unsigned c) {
  unsigned d;
  asm("v_sad_u8 %0, %1, %2, %3" : "=v"(d) : "v"(a), "v"(b), "v"(c));
  return d;
}

template <int CTRL, int RMASK>
static __device__ __forceinline__ int dpp_iadd(int v) {
  int t = __builtin_amdgcn_update_dpp(0, v, CTRL, RMASK, 0xf, false);
  return v + t;
}
static __device__ __forceinline__ int wave_isum64_lane63(int v) {
  v = dpp_iadd<0x111, 0xf>(v);   // row_shr:1
  v = dpp_iadd<0x112, 0xf>(v);   // row_shr:2
  v = dpp_iadd<0x114, 0xf>(v);   // row_shr:4
  v = dpp_iadd<0x118, 0xf>(v);   // row_shr:8
  v = dpp_iadd<0x142, 0xa>(v);   // row_bcast:15 -> rows 1,3
  v = dpp_iadd<0x143, 0xc>(v);   // row_bcast:31 -> rows 2,3
  return v;                      // lane 63 = full sum
}

static __device__ __forceinline__ unsigned q8(float v) {
  return (unsigned)(v * 255.f + 0.5f);   // v in [0,1]
}

__global__ __launch_bounds__(256) void k_minmax(const float* __restrict__ x,
                                                float* __restrict__ ws,
                                                int* __restrict__ out_bits) {
  const float4* x4 = (const float4*)x;
  const int n4 = BB * DD / 4;
  int tid = blockIdx.x * 256 + threadIdx.x;
  if (tid < BB * NCLS) out_bits[tid] = (int)0xFF800000;  // -inf each launch
  float mn = 1e30f, mx = -1e30f;
  for (int i = tid; i < n4; i += 256 * 256) {
    float4 v = x4[i];
    mn = fminf(mn, fminf(fminf(v.x, v.y), fminf(v.z, v.w)));
    mx = fmaxf(mx, fmaxf(fmaxf(v.x, v.y), fmaxf(v.z, v.w)));
  }
#pragma unroll
  for (int off = 32; off; off >>= 1) {
    mn = fminf(mn, __shfl_xor(mn, off, 64));
    mx = fmaxf(mx, __shfl_xor(mx, off, 64));
  }
  __shared__ float smn[4], smx[4];
  int lane = threadIdx.x & 63, wid = threadIdx.x >> 6;
  if (lane == 0) { smn[wid] = mn; smx[wid] = mx; }
  __syncthreads();
  if (threadIdx.x == 0) {
    mn = fminf(fminf(smn[0], smn[1]), fminf(smn[2], smn[3]));
    mx = fmaxf(fmaxf(smx[0], smx[1]), fmaxf(smx[2], smx[3]));
    ws[blockIdx.x] = mn;
    ws[256 + blockIdx.x] = mx;
  }
}

// 320 blocks x 256 thr, ONE launch replacing k_denom + k_code.
// bid < 256: code path -- block reduces the 512 min/max partials ITSELF
//   (no cross-block dependency, no fences), then quantizes rows 4b..4b+3
//   (home XCD b%8, preserving R21's alignment with k_main readers).
// bid 256..319: template path -- wave per template (4/block), quantize raw T
//   (no stats needed) + scale + tsum.
__global__ __launch_bounds__(256) void k_prep(const float* __restrict__ x,
                                              const float* __restrict__ T,
                                              const int* __restrict__ committed,
                                              const int* __restrict__ counts,
                                              float* __restrict__ ws) {
  int tid = threadIdx.x;
  int bid = blockIdx.x;
  int lane = tid & 63, wid = tid >> 6;

  if (bid < 256) {
    // ---- per-block stats reduce (256 partial mins + 256 maxes) ----
    __shared__ float smn[4], smx[4], sbc[2];
    __shared__ int rsum[4];
    float m2 = ws[tid], x2 = ws[256 + tid];
#pragma unroll
    for (int off = 32; off; off >>= 1) {
      m2 = fminf(m2, __shfl_xor(m2, off, 64));
      x2 = fmaxf(x2, __shfl_xor(x2, off, 64));
    }
    if (lane == 0) { smn[wid] = m2; smx[wid] = x2; }
    if (tid < 4) rsum[tid] = 0;
    __syncthreads();
    if (tid == 0) {
      m2 = fminf(fminf(smn[0], smn[1]), fminf(smn[2], smn[3]));
      x2 = fmaxf(fmaxf(smx[0], smx[1]), fmaxf(smx[2], smx[3]));
      sbc[0] = m2;
      sbc[1] = 1.0f / (x2 - m2 + 1e-10f);
    }
    __syncthreads();
    float fmn = sbc[0], finv = sbc[1];
    float na = finv, nb = -fmn * finv;

    int row0 = bid * 4;
    uint4* out4 = (uint4*)((char*)ws + CODED_OFF) + (size_t)bid * 512;
#pragma unroll
    for (int i = 0; i < 2; ++i) {
      int idx = i * 256 + tid;           // 0..511
      int r = idx >> 7;
      int u = idx & 127;
      uint4 o = make_uint4(0, 0, 0, 0);
      if (u < 98) {
        int half = (u >= 49);
        int e = (half ? (u - 49) : u) * 16;
        const float4* xr = (const float4*)(x + (size_t)(row0 + r) * DD + e);
        unsigned w[4];
        int isum = 0;
#pragma unroll
        for (int d = 0; d < 4; ++d) {
          float4 f = xr[d];
          float v0 = na * f.x + nb, v1 = na * f.y + nb;
          float v2 = na * f.z + nb, v3 = na * f.w + nb;
          if (half) { v0 = 1.f - v0; v1 = 1.f - v1; v2 = 1.f - v2; v3 = 1.f - v3; }
          unsigned b0 = q8(v0), b1 = q8(v1), b2 = q8(v2), b3 = q8(v3);
          isum += (int)(b0 + b1 + b2 + b3);
          w[d] = b0 | (b1 << 8) | (b2 << 16) | (b3 << 24);
        }
        o = make_uint4(w[0], w[1], w[2], w[3]);
        atomicAdd(&rsum[r], isum);
      }
      out4[idx] = o;
    }
    __syncthreads();
    if (tid < 4) ((int*)ws)[1536 + row0 + tid] = rsum[tid];
  } else {
    // ---- template path: wave per template, no stats dependency ----
    int m = (bid - 256) * 4 + wid;
    float s = 0.f;
    int isum = 0;
    uint4 pk[2] = {make_uint4(0,0,0,0), make_uint4(0,0,0,0)};
    if (lane < 49) {
      const float4* tp = (const float4*)(T + (size_t)m * TD + lane * 32);
      unsigned w[8];
#pragma unroll
      for (int d = 0; d < 8; ++d) {
        float4 f = tp[d];
        s += (f.x + f.y) + (f.z + f.w);
        unsigned b0 = q8(f.x), b1 = q8(f.y), b2 = q8(f.z), b3 = q8(f.w);
        isum += (int)(b0 + b1 + b2 + b3);
        w[d] = b0 | (b1 << 8) | (b2 << 16) | (b3 << 24);
      }
      pk[0] = make_uint4(w[0], w[1], w[2], w[3]);
      pk[1] = make_uint4(w[4], w[5], w[6], w[7]);
    }
    uint4* u8T = (uint4*)((char*)ws + TMPL_OFF + (size_t)m * RB);
    u8T[lane * 2]     = pk[0];
    u8T[lane * 2 + 1] = pk[1];
#pragma unroll
    for (int off = 32; off; off >>= 1) {
      s += __shfl_xor(s, off, 64);
      isum += __shfl_xor(isum, off, 64);
    }
    if (lane == 0) {
      float denom = ALPHA + s + GAMMA * (float)counts[m];
      ws[512 + m] = committed[m] ? (1.0f / denom) : -1.0f;
      ((int*)ws)[1024 + m] = isum;
    }
  }
}

// grid 4096; XCD-ALIGNED decode: rg = bid & 255, tg = bid >> 8.
// Byte-identical to R21's verified k_main (29.7us best).
__global__ __launch_bounds__(256) void k_main(const int* __restrict__ labels,
                                              const float* __restrict__ ws,
                                              int* __restrict__ out_bits) {
  __shared__ int clsmax[ROWS_PB][NCLS];

  int tid = threadIdx.x;
  int lane = tid & 63, wid = tid >> 6;
  int rg = blockIdx.x & 255;       // low bits -> XCD affinity follows rowgroup
  int tg = blockIdx.x >> 8;
  int row0 = rg * ROWS_PB;
  int m0 = tg * 16 + wid * TPW;

  // ---- issue ALL loads first: 8 template + 8 coded (inline asm) ----
  const uint4* tbase = (const uint4*)((const char*)ws + TMPL_OFF);
  const uint4* cg = (const uint4*)((const char*)ws + CODED_OFF) + (size_t)row0 * 128;
  uint4 tr[TPW][2], cr[ROWS_PB][2];
#pragma unroll
  for (int t = 0; t < TPW; ++t) {
    const uint4* a0 = tbase + (size_t)(m0 + t) * 128 + lane;
    const uint4* a1 = a0 + 64;
    asm volatile("global_load_dwordx4 %0, %1, off" : "=v"(tr[t][0]) : "v"(a0));
    asm volatile("global_load_dwordx4 %0, %1, off" : "=v"(tr[t][1]) : "v"(a1));
  }
#pragma unroll
  for (int r = 0; r < ROWS_PB; ++r) {
    const uint4* b0 = cg + r * 128 + lane;
    const uint4* b1 = b0 + 64;
    asm volatile("global_load_dwordx4 %0, %1, off" : "=v"(cr[r][0]) : "v"(b0));
    asm volatile("global_load_dwordx4 %0, %1, off" : "=v"(cr[r][1]) : "v"(b1));
  }

  // scalar-ish metadata loads (overlap with VMEM)
  float scv[TPW];
  int lbv[TPW], tsv[TPW];
#pragma unroll
  for (int t = 0; t < TPW; ++t) {
    scv[t] = ws[512 + m0 + t];
    lbv[t] = labels[m0 + t];
    tsv[t] = ((const int*)ws)[1024 + m0 + t];
  }
  int myrow = ((const int*)ws)[1536 + row0 + (lane & 3)];

  if (tid < ROWS_PB * NCLS) clsmax[tid / NCLS][tid % NCLS] = (int)0xFF800000;

  // single drain; fence register-only SAD from hoisting above (rule #18)
  asm volatile("s_waitcnt vmcnt(0)" ::: "memory");
  __builtin_amdgcn_sched_barrier(0);
  __syncthreads();   // clsmax init visible

  // ---- compute: 128 v_sad_u8, zero memory ops ----
  unsigned acc[TPW][ROWS_PB];
#pragma unroll
  for (int t = 0; t < TPW; ++t)
#pragma unroll
    for (int r = 0; r < ROWS_PB; ++r) acc[t][r] = 0;

#pragma unroll
  for (int r = 0; r < ROWS_PB; ++r) {
#pragma unroll
    for (int t = 0; t < TPW; ++t) {
      unsigned a = acc[t][r];
      a = sad_u8(cr[r][0].x, tr[t][0].x, a);
      a = sad_u8(cr[r][0].y, tr[t][0].y, a);
      a = sad_u8(cr[r][0].z, tr[t][0].z, a);
      a = sad_u8(cr[r][0].w, tr[t][0].w, a);
      a = sad_u8(cr[r][1].x, tr[t][1].x, a);
      a = sad_u8(cr[r][1].y, tr[t][1].y, a);
      a = sad_u8(cr[r][1].z, tr[t][1].z, a);
      a = sad_u8(cr[r][1].w, tr[t][1].w, a);
      acc[t][r] = a;
    }
  }

  // ---- reduce: 16 DPP sums; scatter lane = t*4+r computes choice ----
  float sc = -1.f; int lb = 0, tsum_s = 0;
#pragma unroll
  for (int t = 0; t < TPW; ++t)
    if ((lane >> 2) == t) { sc = scv[t]; lb = lbv[t]; tsum_s = tsv[t]; }

  float vout = 0.f;
#pragma unroll
  for (int t = 0; t < TPW; ++t)
#pragma unroll
    for (int r = 0; r < ROWS_PB; ++r) {
      int s = wave_isum64_lane63((int)acc[t][r]);
      int g = __builtin_amdgcn_readlane(s, 63);
      if (lane == t * 4 + r)
        vout = (float)(myrow + tsum_s - g) * (sc * (0.5f / 255.f));
    }

  if (lane < 16 && sc > 0.f)
    atomicMax(&clsmax[lane & 3][lb], __float_as_int(vout));
  __syncthreads();

  if (tid < ROWS_PB * NCLS) {
    int rr = tid / NCLS, cc = tid - rr * NCLS;
    int bits = clsmax[rr][cc];
    if (bits != (int)0xFF800000)
      atomicMax(&out_bits[(row0 + rr) * NCLS + cc], bits);
  }
}

extern "C" void kernel_launch(void* const* d_in, const int* in_sizes, int n_in,
                              void* d_out, int out_size, void* d_ws, size_t ws_size,
                              hipStream_t stream) {
  const float* x = (const float*)d_in[0];
  const float* T = (const float*)d_in[1];
  const int* committed = (const int*)d_in[2];
  const int* labels = (const int*)d_in[3];
  const int* counts = (const int*)d_in[4];
  int* out_bits = (int*)d_out;
  float* ws = (float*)d_ws;

  k_minmax<<<dim3(256), dim3(256), 0, stream>>>(x, ws, out_bits);
  k_prep<<<dim3(320), dim3(256), 0, stream>>>(x, T, committed, counts, ws);
  k_main<<<dim3(NBLK), dim3(256), 0, stream>>>(labels, ws, out_bits);
}

// Round 26
// 25.349 us; speedup vs baseline: 5.6463x; 1.0623x over previous
//
#include <hip/hip_runtime.h>
#include <math.h>

#define ALPHA 0.001f
#define GAMMA 0.01f
#define DD 784
#define TD 1568          // 2*D floats per template row
#define RB 2048          // padded u8 row bytes (coded & templates)
#define MM 256
#define BB 1024
#define NCLS 10
#define ROWS_PB 4
#define TPW 4
#define NBLK 4096        // 16 tgroups (high bits) x 256 rowgroups (low bits)

// ws layout:
//   f32[0..255] partial min | f32[256..511] partial max
//   f32[512..767] scale[m]
//   i32[1024..1279] tsum[m]
//   i32[1536..2559] rowsum[row]
//   byte 16384:  u8 templates 256 x 2048  (512 KB)
//   byte 540672: u8 coded    1024 x 2048  (2 MB)

#define TMPL_OFF 16384
#define CODED_OFF 540672

static __device__ __forceinline__ unsigned sad_u8(unsigned a, unsigned b, unsigned c) {
  unsigned d;
  asm("v_sad_u8 %0, %1, %2, %3" : "=v"(d) : "v"(a), "v"(b), "v"(c));
  return d;
}

template <int CTRL>
static __device__ __forceinline__ unsigned dppx(unsigned v) {
  return (unsigned)__builtin_amdgcn_update_dpp(0, (int)v, CTRL, 0xf, 0xf, false);
}

static __device__ __forceinline__ unsigned q8(float v) {
  return (unsigned)(v * 255.f + 0.5f);   // v in [0,1]
}

__global__ __launch_bounds__(256) void k_minmax(const float* __restrict__ x,
                                                float* __restrict__ ws,
                                                int* __restrict__ out_bits) {
  const float4* x4 = (const float4*)x;
  const int n4 = BB * DD / 4;
  int tid = blockIdx.x * 256 + threadIdx.x;
  if (tid < BB * NCLS) out_bits[tid] = (int)0xFF800000;  // -inf each launch
  float mn = 1e30f, mx = -1e30f;
  for (int i = tid; i < n4; i += 256 * 256) {
    float4 v = x4[i];
    mn = fminf(mn, fminf(fminf(v.x, v.y), fminf(v.z, v.w)));
    mx = fmaxf(mx, fmaxf(fmaxf(v.x, v.y), fmaxf(v.z, v.w)));
  }
#pragma unroll
  for (int off = 32; off; off >>= 1) {
    mn = fminf(mn, __shfl_xor(mn, off, 64));
    mx = fmaxf(mx, __shfl_xor(mx, off, 64));
  }
  __shared__ float smn[4], smx[4];
  int lane = threadIdx.x & 63, wid = threadIdx.x >> 6;
  if (lane == 0) { smn[wid] = mn; smx[wid] = mx; }
  __syncthreads();
  if (threadIdx.x == 0) {
    mn = fminf(fminf(smn[0], smn[1]), fminf(smn[2], smn[3]));
    mx = fmaxf(fmaxf(smx[0], smx[1]), fmaxf(smx[2], smx[3]));
    ws[blockIdx.x] = mn;
    ws[256 + blockIdx.x] = mx;
  }
}

// 320 blocks x 256 thr, ONE launch replacing k_denom + k_code (R25-verified).
__global__ __launch_bounds__(256) void k_prep(const float* __restrict__ x,
                                              const float* __restrict__ T,
                                              const int* __restrict__ committed,
                                              const int* __restrict__ counts,
                                              float* __restrict__ ws) {
  int tid = threadIdx.x;
  int bid = blockIdx.x;
  int lane = tid & 63, wid = tid >> 6;

  if (bid < 256) {
    // ---- per-block stats reduce, then quantize rows 4b..4b+3 ----
    __shared__ float smn[4], smx[4], sbc[2];
    __shared__ int rsum[4];
    float m2 = ws[tid], x2 = ws[256 + tid];
#pragma unroll
    for (int off = 32; off; off >>= 1) {
      m2 = fminf(m2, __shfl_xor(m2, off, 64));
      x2 = fmaxf(x2, __shfl_xor(x2, off, 64));
    }
    if (lane == 0) { smn[wid] = m2; smx[wid] = x2; }
    if (tid < 4) rsum[tid] = 0;
    __syncthreads();
    if (tid == 0) {
      m2 = fminf(fminf(smn[0], smn[1]), fminf(smn[2], smn[3]));
      x2 = fmaxf(fmaxf(smx[0], smx[1]), fmaxf(smx[2], smx[3]));
      sbc[0] = m2;
      sbc[1] = 1.0f / (x2 - m2 + 1e-10f);
    }
    __syncthreads();
    float fmn = sbc[0], finv = sbc[1];
    float na = finv, nb = -fmn * finv;

    int row0 = bid * 4;
    uint4* out4 = (uint4*)((char*)ws + CODED_OFF) + (size_t)bid * 512;
#pragma unroll
    for (int i = 0; i < 2; ++i) {
      int idx = i * 256 + tid;           // 0..511
      int r = idx >> 7;
      int u = idx & 127;
      uint4 o = make_uint4(0, 0, 0, 0);
      if (u < 98) {
        int half = (u >= 49);
        int e = (half ? (u - 49) : u) * 16;
        const float4* xr = (const float4*)(x + (size_t)(row0 + r) * DD + e);
        unsigned w[4];
        int isum = 0;
#pragma unroll
        for (int d = 0; d < 4; ++d) {
          float4 f = xr[d];
          float v0 = na * f.x + nb, v1 = na * f.y + nb;
          float v2 = na * f.z + nb, v3 = na * f.w + nb;
          if (half) { v0 = 1.f - v0; v1 = 1.f - v1; v2 = 1.f - v2; v3 = 1.f - v3; }
          unsigned b0 = q8(v0), b1 = q8(v1), b2 = q8(v2), b3 = q8(v3);
          isum += (int)(b0 + b1 + b2 + b3);
          w[d] = b0 | (b1 << 8) | (b2 << 16) | (b3 << 24);
        }
        o = make_uint4(w[0], w[1], w[2], w[3]);
        atomicAdd(&rsum[r], isum);
      }
      out4[idx] = o;
    }
    __syncthreads();
    if (tid < 4) ((int*)ws)[1536 + row0 + tid] = rsum[tid];
  } else {
    // ---- template path: wave per template ----
    int m = (bid - 256) * 4 + wid;
    float s = 0.f;
    int isum = 0;
    uint4 pk[2] = {make_uint4(0,0,0,0), make_uint4(0,0,0,0)};
    if (lane < 49) {
      const float4* tp = (const float4*)(T + (size_t)m * TD + lane * 32);
      unsigned w[8];
#pragma unroll
      for (int d = 0; d < 8; ++d) {
        float4 f = tp[d];
        s += (f.x + f.y) + (f.z + f.w);
        unsigned b0 = q8(f.x), b1 = q8(f.y), b2 = q8(f.z), b3 = q8(f.w);
        isum += (int)(b0 + b1 + b2 + b3);
        w[d] = b0 | (b1 << 8) | (b2 << 16) | (b3 << 24);
      }
      pk[0] = make_uint4(w[0], w[1], w[2], w[3]);
      pk[1] = make_uint4(w[4], w[5], w[6], w[7]);
    }
    uint4* u8T = (uint4*)((char*)ws + TMPL_OFF + (size_t)m * RB);
    u8T[lane * 2]     = pk[0];
    u8T[lane * 2 + 1] = pk[1];
#pragma unroll
    for (int off = 32; off; off >>= 1) {
      s += __shfl_xor(s, off, 64);
      isum += __shfl_xor(isum, off, 64);
    }
    if (lane == 0) {
      float denom = ALPHA + s + GAMMA * (float)counts[m];
      ws[512 + m] = committed[m] ? (1.0f / denom) : -1.0f;
      ((int*)ws)[1024 + m] = isum;
    }
  }
}

// grid 4096; XCD-aligned decode (R21/R25). Compute core identical; reduce
// replaced by PACKED multi-acc reduction: acc-index bits {0,1,2,3} pack
// against lane bits {0,1,3,4} at xor-offsets {1,2,8,16}; folds at xor 4,32.
// Lane l ends holding the full 64-lane total of acc i=(l&3)|((l>>1)&0xC) --
// no readlane, no scatter chain. Integer adds: bit-exact vs R25.
__global__ __launch_bounds__(256) void k_main(const int* __restrict__ labels,
                                              const float* __restrict__ ws,
                                              int* __restrict__ out_bits) {
  __shared__ int clsmax[ROWS_PB][NCLS];

  int tid = threadIdx.x;
  int lane = tid & 63, wid = tid >> 6;
  int rg = blockIdx.x & 255;       // low bits -> XCD affinity follows rowgroup
  int tg = blockIdx.x >> 8;
  int row0 = rg * ROWS_PB;
  int m0 = tg * 16 + wid * TPW;

  // ---- issue ALL loads first: 8 template + 8 coded (inline asm) ----
  const uint4* tbase = (const uint4*)((const char*)ws + TMPL_OFF);
  const uint4* cg = (const uint4*)((const char*)ws + CODED_OFF) + (size_t)row0 * 128;
  uint4 tr[TPW][2], cr[ROWS_PB][2];
#pragma unroll
  for (int t = 0; t < TPW; ++t) {
    const uint4* a0 = tbase + (size_t)(m0 + t) * 128 + lane;
    const uint4* a1 = a0 + 64;
    asm volatile("global_load_dwordx4 %0, %1, off" : "=v"(tr[t][0]) : "v"(a0));
    asm volatile("global_load_dwordx4 %0, %1, off" : "=v"(tr[t][1]) : "v"(a1));
  }
#pragma unroll
  for (int r = 0; r < ROWS_PB; ++r) {
    const uint4* b0 = cg + r * 128 + lane;
    const uint4* b1 = b0 + 64;
    asm volatile("global_load_dwordx4 %0, %1, off" : "=v"(cr[r][0]) : "v"(b0));
    asm volatile("global_load_dwordx4 %0, %1, off" : "=v"(cr[r][1]) : "v"(b1));
  }

  // metadata: t for this lane = bits {3,4} of lane (packed-reduce layout)
  int tsel = ((lane >> 3) & 1) | ((lane >> 3) & 2);
  float scv[TPW];
  int lbv[TPW], tsv[TPW];
#pragma unroll
  for (int t = 0; t < TPW; ++t) {
    scv[t] = ws[512 + m0 + t];
    lbv[t] = labels[m0 + t];
    tsv[t] = ((const int*)ws)[1024 + m0 + t];
  }
  int myrow = ((const int*)ws)[1536 + row0 + (lane & 3)];

  if (tid < ROWS_PB * NCLS) clsmax[tid / NCLS][tid % NCLS] = (int)0xFF800000;

  // single drain; fence register-only SAD from hoisting above (rule #18)
  asm volatile("s_waitcnt vmcnt(0)" ::: "memory");
  __builtin_amdgcn_sched_barrier(0);
  __syncthreads();   // clsmax init visible

  // ---- compute: 128 v_sad_u8 into flat acc[i], i = t*4 + r ----
  unsigned accf[16];
#pragma unroll
  for (int i = 0; i < 16; ++i) accf[i] = 0;

#pragma unroll
  for (int r = 0; r < ROWS_PB; ++r) {
#pragma unroll
    for (int t = 0; t < TPW; ++t) {
      unsigned a = accf[t * 4 + r];
      a = sad_u8(cr[r][0].x, tr[t][0].x, a);
      a = sad_u8(cr[r][0].y, tr[t][0].y, a);
      a = sad_u8(cr[r][0].z, tr[t][0].z, a);
      a = sad_u8(cr[r][0].w, tr[t][0].w, a);
      a = sad_u8(cr[r][1].x, tr[t][1].x, a);
      a = sad_u8(cr[r][1].y, tr[t][1].y, a);
      a = sad_u8(cr[r][1].z, tr[t][1].z, a);
      a = sad_u8(cr[r][1].w, tr[t][1].w, a);
      accf[t * 4 + r] = a;
    }
  }

  // ---- packed reduce: dest-lane bits {0,1,3,4} <- acc bits {0,1,2,3} ----
  bool lb0 = (lane & 1) != 0, lb1 = (lane & 2) != 0;
  bool lb3 = (lane & 8) != 0, lb4 = (lane & 16) != 0;

  unsigned r8[8];
#pragma unroll
  for (int k = 0; k < 8; ++k) {          // pack acc bit0 vs lane bit0 (xor1)
    unsigned e = accf[2 * k],     es = e + dppx<0xB1>(e);   // quad_perm [1,0,3,2]
    unsigned o = accf[2 * k + 1], os = o + dppx<0xB1>(o);
    r8[k] = lb0 ? os : es;
  }
  unsigned r4[4];
#pragma unroll
  for (int k = 0; k < 4; ++k) {          // pack acc bit1 vs lane bit1 (xor2)
    unsigned e = r8[2 * k],     es = e + dppx<0x4E>(e);     // quad_perm [2,3,0,1]
    unsigned o = r8[2 * k + 1], os = o + dppx<0x4E>(o);
    r4[k] = lb1 ? os : es;
  }
  unsigned r2[2];
#pragma unroll
  for (int k = 0; k < 2; ++k) {          // pack acc bit2 vs lane bit3 (xor8 = row_ror:8)
    unsigned e = r4[2 * k],     es = e + dppx<0x128>(e);
    unsigned o = r4[2 * k + 1], os = o + dppx<0x128>(o);
    r2[k] = lb3 ? os : es;
  }
  unsigned r1;
  {                                      // pack acc bit3 vs lane bit4 (xor16)
    unsigned e = r2[0], es = e + (unsigned)__shfl_xor((int)r2[0], 16, 64);
    unsigned o = r2[1], os = o + (unsigned)__shfl_xor((int)r2[1], 16, 64);
    r1 = lb4 ? os : es;
  }
  r1 += (unsigned)__shfl_xor((int)r1, 4, 64);    // fold lane bit2
  r1 += (unsigned)__shfl_xor((int)r1, 32, 64);   // fold lane bit5
  // lane l now holds total of acc i = (l&3) | ((l>>1)&0xC); r = l&3, t = tsel

  float sc = -1.f; int lb = 0, tsum_s = 0;
#pragma unroll
  for (int t = 0; t < TPW; ++t)
    if (tsel == t) { sc = scv[t]; lb = lbv[t]; tsum_s = tsv[t]; }

  float vout = (float)(myrow + tsum_s - (int)r1) * (sc * (0.5f / 255.f));

  if ((lane & 36) == 0 && sc > 0.f)      // bits 2,5 zero -> 16 unique lanes
    atomicMax(&clsmax[lane & 3][lb], __float_as_int(vout));
  __syncthreads();

  if (tid < ROWS_PB * NCLS) {
    int rr = tid / NCLS, cc = tid - rr * NCLS;
    int bits = clsmax[rr][cc];
    if (bits != (int)0xFF800000)
      atomicMax(&out_bits[(row0 + rr) * NCLS + cc], bits);
  }
}

extern "C" void kernel_launch(void* const* d_in, const int* in_sizes, int n_in,
                              void* d_out, int out_size, void* d_ws, size_t ws_size,
                              hipStream_t stream) {
  const float* x = (const float*)d_in[0];
  const float* T = (const float*)d_in[1];
  const int* committed = (const int*)d_in[2];
  const int* labels = (const int*)d_in[3];
  const int* counts = (const int*)d_in[4];
  int* out_bits = (int*)d_out;
  float* ws = (float*)d_ws;

  k_minmax<<<dim3(256), dim3(256), 0, stream>>>(x, ws, out_bits);
  k_prep<<<dim3(320), dim3(256), 0, stream>>>(x, T, committed, counts, ws);
  k_main<<<dim3(NBLK), dim3(256), 0, stream>>>(labels, ws, out_bits);
}